// Round 1
// baseline (249.095 us; speedup 1.0000x reference)
//
#include <hip/hip_runtime.h>

#define S   512
#define OUT 512
#define NB  8
#define CB  32

// ---------------------------------------------------------------------------
// Kernel 1: per-(axis,batch) inverse-CDF sampling coords.
// blockIdx.x in [0,16): axis = bid>>3 (0 = x from attx, 1 = y from atty),
// n = bid&7. 512 threads, one per input cell / output pixel.
// Emits i0 (int) and lerp weight w (float) for each output position.
// Double precision throughout: negligible cost at this size, keeps the
// cumsum / searchsorted numerically tight vs the reference.
// ---------------------------------------------------------------------------
__global__ __launch_bounds__(512) void coords_kernel(
    const float* __restrict__ attx, const float* __restrict__ atty,
    int* __restrict__ idx_out, float* __restrict__ w_out)
{
  __shared__ double sc[S];
  __shared__ double red[8];
  const int tid  = threadIdx.x;
  const int n    = blockIdx.x & 7;
  const int axis = blockIdx.x >> 3;
  const float* att = (axis == 0 ? attx : atty) + n * S;

  double a = (double)att[tid];

  // --- block sum ---
  double v = a;
#pragma unroll
  for (int off = 32; off > 0; off >>= 1) v += __shfl_down(v, off);
  if ((tid & 63) == 0) red[tid >> 6] = v;
  __syncthreads();
  double total = red[0] + red[1] + red[2] + red[3] +
                 red[4] + red[5] + red[6] + red[7];

  a = a / total * (double)OUT;               // sum == OUT
  const double thr = (double)(4 * OUT) / (double)S;

  // --- 5 clip + redistribute iterations ---
  for (int it = 0; it < 5; ++it) {
    a = a < thr ? a : thr;
    __syncthreads();                          // protect red[] reuse
    v = a;
#pragma unroll
    for (int off = 32; off > 0; off >>= 1) v += __shfl_down(v, off);
    if ((tid & 63) == 0) red[tid >> 6] = v;
    __syncthreads();
    double t2 = red[0] + red[1] + red[2] + red[3] +
                red[4] + red[5] + red[6] + red[7];
    a += ((double)OUT - t2) / (double)S;
  }

  // --- inclusive scan (Hillis-Steele) into LDS ---
  sc[tid] = a;
  __syncthreads();
  for (int off = 1; off < S; off <<= 1) {
    double t = (tid >= off) ? sc[tid - off] : 0.0;
    __syncthreads();
    sc[tid] += t;
    __syncthreads();
  }

  const double step = sc[S - 1] / (double)OUT;
  const double tgt  = step * (double)(tid + 1);

  // --- lower_bound: first j with sc[j] >= tgt ---
  int lo = 0, hi = S;
  while (lo < hi) {
    int mid = (lo + hi) >> 1;
    if (sc[mid] < tgt) lo = mid + 1; else hi = mid;
  }
  int j = lo < S - 1 ? lo : S - 1;

  double right = sc[j];
  double left  = (j > 0) ? sc[j - 1] : 0.0;
  double denom = right - left;
  if (denom < 1e-8) denom = 1e-8;
  double frac = (tgt - left) / denom;
  frac = frac < 0.0 ? 0.0 : (frac > 1.0 ? 1.0 : frac);

  // coord = (j+frac)/S*2-1 ; p = (coord+1)*0.5*(S-1) = (j+frac)/S*(S-1)
  double p   = ((double)j + frac) / (double)S * (double)(S - 1);
  double p0f = floor(p);
  double w   = p - p0f;
  int i0 = (int)p0f;
  i0 = i0 < 0 ? 0 : (i0 > S - 1 ? S - 1 : i0);

  idx_out[blockIdx.x * S + tid] = i0;
  w_out[blockIdx.x * S + tid]   = (float)w;
}

// ---------------------------------------------------------------------------
// Kernel 2: fused separable bilinear gather.
// One block = (n, c, 4 consecutive output rows). 512 threads as (128,4):
// threadIdx.y = row in tile, threadIdx.x covers 128 groups of 4 ox.
// x-weights staged in LDS; one float4 store per thread.
// ---------------------------------------------------------------------------
__global__ __launch_bounds__(512) void sample_kernel(
    const float* __restrict__ data, const int* __restrict__ ws_idx,
    const float* __restrict__ ws_w, float* __restrict__ out)
{
  __shared__ int   s_ix[OUT];
  __shared__ float s_wx[OUT];

  const int t    = blockIdx.x;
  const int tile = t & 127;          // 128 tiles of 4 rows
  const int c    = (t >> 7) & 31;
  const int n    = t >> 12;

  const int tid = threadIdx.y * 128 + threadIdx.x;
  s_ix[tid] = ws_idx[n * S + tid];
  s_wx[tid] = ws_w[n * S + tid];
  __syncthreads();

  const int oy  = tile * 4 + threadIdx.y;
  const int i0y = ws_idx[8 * S + n * S + oy];
  const float wy = ws_w[8 * S + n * S + oy];
  const int i1y = (i0y + 1 < S) ? i0y + 1 : S - 1;

  const float* __restrict__ rowA =
      data + (((size_t)(n * CB + c) * S) + i0y) * (size_t)S;
  const float* __restrict__ rowB =
      data + (((size_t)(n * CB + c) * S) + i1y) * (size_t)S;

  float v[4];
#pragma unroll
  for (int k = 0; k < 4; ++k) {
    const int ox  = threadIdx.x * 4 + k;
    const int i0x = s_ix[ox];
    const float wx = s_wx[ox];
    const int i1x = (i0x + 1 < S) ? i0x + 1 : S - 1;
    const float a = rowA[i0x];
    const float b = rowA[i1x];
    const float p = rowB[i0x];
    const float q = rowB[i1x];
    const float top = a + wx * (b - a);
    const float bot = p + wx * (q - p);
    v[k] = top + wy * (bot - top);
  }

  float4* o = (float4*)(out + (((size_t)(n * CB + c) * (size_t)OUT) + oy) * (size_t)OUT
                            + threadIdx.x * 4);
  *o = make_float4(v[0], v[1], v[2], v[3]);
}

extern "C" void kernel_launch(void* const* d_in, const int* in_sizes, int n_in,
                              void* d_out, int out_size, void* d_ws, size_t ws_size,
                              hipStream_t stream) {
  const float* data = (const float*)d_in[0];
  const float* attx = (const float*)d_in[1];
  const float* atty = (const float*)d_in[2];
  float* out = (float*)d_out;

  // Workspace layout: [2*8*512 ints (i0 x then y)] [2*8*512 floats (w x then y)]
  int*   ws_idx = (int*)d_ws;
  float* ws_w   = (float*)((char*)d_ws + 2 * NB * S * sizeof(int));

  coords_kernel<<<16, 512, 0, stream>>>(attx, atty, ws_idx, ws_w);

  const int nblocks = NB * CB * (OUT / 4);   // 8*32*128 = 32768
  sample_kernel<<<nblocks, dim3(128, 4), 0, stream>>>(data, ws_idx, ws_w, out);
}

// Round 2
// 140.606 us; speedup vs baseline: 1.7716x; 1.7716x over previous
//
#include <hip/hip_runtime.h>

#define S   512
#define OUT 512
#define NB  8
#define CB  32

// ---------------------------------------------------------------------------
// Kernel 1: per-(axis,batch) inverse-CDF sampling coords (unchanged, passed).
// ---------------------------------------------------------------------------
__global__ __launch_bounds__(512) void coords_kernel(
    const float* __restrict__ attx, const float* __restrict__ atty,
    int* __restrict__ idx_out, float* __restrict__ w_out)
{
  __shared__ double sc[S];
  __shared__ double red[8];
  const int tid  = threadIdx.x;
  const int n    = blockIdx.x & 7;
  const int axis = blockIdx.x >> 3;
  const float* att = (axis == 0 ? attx : atty) + n * S;

  double a = (double)att[tid];

  double v = a;
#pragma unroll
  for (int off = 32; off > 0; off >>= 1) v += __shfl_down(v, off);
  if ((tid & 63) == 0) red[tid >> 6] = v;
  __syncthreads();
  double total = red[0] + red[1] + red[2] + red[3] +
                 red[4] + red[5] + red[6] + red[7];

  a = a / total * (double)OUT;
  const double thr = (double)(4 * OUT) / (double)S;

  for (int it = 0; it < 5; ++it) {
    a = a < thr ? a : thr;
    __syncthreads();
    v = a;
#pragma unroll
    for (int off = 32; off > 0; off >>= 1) v += __shfl_down(v, off);
    if ((tid & 63) == 0) red[tid >> 6] = v;
    __syncthreads();
    double t2 = red[0] + red[1] + red[2] + red[3] +
                red[4] + red[5] + red[6] + red[7];
    a += ((double)OUT - t2) / (double)S;
  }

  sc[tid] = a;
  __syncthreads();
  for (int off = 1; off < S; off <<= 1) {
    double t = (tid >= off) ? sc[tid - off] : 0.0;
    __syncthreads();
    sc[tid] += t;
    __syncthreads();
  }

  const double step = sc[S - 1] / (double)OUT;
  const double tgt  = step * (double)(tid + 1);

  int lo = 0, hi = S;
  while (lo < hi) {
    int mid = (lo + hi) >> 1;
    if (sc[mid] < tgt) lo = mid + 1; else hi = mid;
  }
  int j = lo < S - 1 ? lo : S - 1;

  double right = sc[j];
  double left  = (j > 0) ? sc[j - 1] : 0.0;
  double denom = right - left;
  if (denom < 1e-8) denom = 1e-8;
  double frac = (tgt - left) / denom;
  frac = frac < 0.0 ? 0.0 : (frac > 1.0 ? 1.0 : frac);

  double p   = ((double)j + frac) / (double)S * (double)(S - 1);
  double p0f = floor(p);
  double w   = p - p0f;
  int i0 = (int)p0f;
  i0 = i0 < 0 ? 0 : (i0 > S - 1 ? S - 1 : i0);

  idx_out[blockIdx.x * S + tid] = i0;
  w_out[blockIdx.x * S + tid]   = (float)w;
}

// ---------------------------------------------------------------------------
// Kernel 2 (v2): one block per (n, c, output row). Stage the two needed
// input rows into LDS with coalesced float4 loads, gather along x from LDS,
// write one full contiguous output row. XCD swizzle keeps each (n,c) plane's
// 512 row-blocks on one XCD so the ~2x row re-read hits that XCD's L2.
// ---------------------------------------------------------------------------
__global__ __launch_bounds__(256) void sample_kernel(
    const float* __restrict__ data, const int* __restrict__ ws_idx,
    const float* __restrict__ ws_w, float* __restrict__ out)
{
  __shared__ float rA[S];
  __shared__ float rB[S];

  // 131072 blocks total; 131072 % 8 == 0 -> bijective XCD swizzle.
  int b = (int)blockIdx.x;
  b = (b & 7) * (NB * CB * OUT / 8) + (b >> 3);
  const int oy = b & (OUT - 1);
  const int c  = (b >> 9) & (CB - 1);
  const int n  = b >> 14;

  const int tid = threadIdx.x;

  const int   i0y = ws_idx[8 * S + n * S + oy];   // broadcast read
  const float wy  = ws_w [8 * S + n * S + oy];
  const int   i1y = (i0y + 1 < S) ? i0y + 1 : S - 1;

  const float4* rowA = (const float4*)(data + (((size_t)(n * CB + c) * S) + i0y) * (size_t)S);
  const float4* rowB = (const float4*)(data + (((size_t)(n * CB + c) * S) + i1y) * (size_t)S);

  // stage: 128 float4 per row; threads 0-127 -> rowA, 128-255 -> rowB
  if (tid < 128) ((float4*)rA)[tid]       = rowA[tid];
  else           ((float4*)rB)[tid - 128] = rowB[tid - 128];
  __syncthreads();

  // each thread computes two adjacent output pixels, stores a float2
  float v[2];
#pragma unroll
  for (int k = 0; k < 2; ++k) {
    const int ox  = tid * 2 + k;
    const int   i0x = ws_idx[n * S + ox];
    const float wx  = ws_w [n * S + ox];
    const int   i1x = (i0x + 1 < S) ? i0x + 1 : S - 1;
    const float a  = rA[i0x];
    const float bb = rA[i1x];
    const float p  = rB[i0x];
    const float q  = rB[i1x];
    const float top = a + wx * (bb - a);
    const float bot = p + wx * (q - p);
    v[k] = top + wy * (bot - top);
  }

  float2* o = (float2*)(out + (((size_t)(n * CB + c) * (size_t)OUT) + oy) * (size_t)OUT
                            + tid * 2);
  *o = make_float2(v[0], v[1]);
}

extern "C" void kernel_launch(void* const* d_in, const int* in_sizes, int n_in,
                              void* d_out, int out_size, void* d_ws, size_t ws_size,
                              hipStream_t stream) {
  const float* data = (const float*)d_in[0];
  const float* attx = (const float*)d_in[1];
  const float* atty = (const float*)d_in[2];
  float* out = (float*)d_out;

  int*   ws_idx = (int*)d_ws;
  float* ws_w   = (float*)((char*)d_ws + 2 * NB * S * sizeof(int));

  coords_kernel<<<16, 512, 0, stream>>>(attx, atty, ws_idx, ws_w);

  const int nblocks = NB * CB * OUT;   // 131072
  sample_kernel<<<nblocks, 256, 0, stream>>>(data, ws_idx, ws_w, out);
}